// Round 18
// baseline (98.360 us; speedup 1.0000x reference)
//
#include <hip/hip_runtime.h>
#include <hip/hip_fp16.h>
#include <math.h>

// GCNConv QNet: out = tanh( (segsum(x[src]*norm, dst) + selfloop) @ W1 + b1 ) @ W2 + b2
// norm = dinv[src]*dinv[dst], dinv = rsqrt(in_degree + 1).
// Aggregation in 32-dim obs space (W1 applied AFTER segment_sum — linearity).
// R18: k_fused reverted to R15 exactly (proven 47.5us; R16 pipelining neutral,
// R17 DS/transpose regressed). One change: SPLIT_E 4096->2048 so k_split runs
// 782 blocks (~3/CU) instead of 391 (~1.5/CU) — occupancy for its edge loads.

#define NOBS 32
#define NMID 64
#define NACT 8
#define BSH 7
#define BNODES 128           // nodes per bucket
#define CAP 4096             // max entries per bucket (mean ~2046)
#define ARENA_B 16384        // bytes per bucket arena (= CAP*4)
#define SPLIT_E 2048         // edges per split block (R18: was 4096)
#define NPW 4                // nodes per wave in k_fused

typedef _Float16 half2v __attribute__((ext_vector_type(2)));

__device__ __forceinline__ bool edges_i64(const int* ei) {
    return (ei[1] | ei[3] | ei[5] | ei[7]) == 0;
}

// tanh(x) = 1 - 2/(1+e^{2x}); exact at +-inf, ~1e-5 rel err, branch-free.
__device__ __forceinline__ float fast_tanh(float x) {
    float t = __expf(2.f * x);
    return 1.f - 2.f * __builtin_amdgcn_rcpf(1.f + t);
}

__device__ __forceinline__ unsigned rlu(unsigned v, int lane) {
    return (unsigned)__builtin_amdgcn_readlane((int)v, lane);
}

// packed half2 add on raw bits (v_pk_add_f16)
__device__ __forceinline__ unsigned padd(unsigned a, unsigned b) {
    __half2 r = __hadd2(__builtin_bit_cast(__half2, a),
                        __builtin_bit_cast(__half2, b));
    return __builtin_bit_cast(unsigned, r);
}

// c += a.x*b.x + a.y*b.y in f32 (v_dot2_f32_f16)
__device__ __forceinline__ float fdot2u(unsigned a, unsigned b, float c) {
    return __builtin_amdgcn_fdot2(__builtin_bit_cast(half2v, a),
                                  __builtin_bit_cast(half2v, b), c, false);
}

// Multisplit: bin SPLIT_E edges by dst-bucket. Edges live in registers
// (8/thread); LDS = grouped output + counters (~17 KB).
__global__ __launch_bounds__(256) void k_split(
        const int* __restrict__ ei, int* __restrict__ gcnt,
        unsigned int* __restrict__ arena, long long e, int nbuckets) {
    __shared__ int sbuf[SPLIT_E];   // bucket-grouped entries (8 KB)
    __shared__ int offs[1024];
    __shared__ int cur[1024];
    __shared__ int tsum[256];
    const int tid = threadIdx.x;
    int eb[8];
    int bk[8];

    for (int b = tid; b < 1024; b += 256) cur[b] = 0;  // cur = hist
    __syncthreads();

    const long long base = (long long)blockIdx.x * SPLIT_E;
    const bool i64 = edges_i64(ei);
    const long long* e64 = (const long long*)ei;
#pragma unroll
    for (int j = 0; j < 4; ++j) {
        const int kk = j * 512 + tid * 2;
        const long long ge = base + kk;
        const bool v0 = ge < e, v1 = ge + 1 < e;
        int s0 = 0, d0 = 0, s1 = 0, d1 = 0;
        if (v1) {  // paired loads
            if (i64) {
                ulonglong2 sp = *(const ulonglong2*)(e64 + ge);
                ulonglong2 dp = *(const ulonglong2*)(e64 + e + ge);
                s0 = (int)sp.x; s1 = (int)sp.y; d0 = (int)dp.x; d1 = (int)dp.y;
            } else {
                int2 sp = *(const int2*)(ei + ge);
                int2 dp = *(const int2*)(ei + e + ge);
                s0 = sp.x; s1 = sp.y; d0 = dp.x; d1 = dp.y;
            }
        } else if (v0) {
            if (i64) { s0 = (int)e64[ge]; d0 = (int)e64[e + ge]; }
            else     { s0 = ei[ge];       d0 = ei[e + ge]; }
        }
        eb[2 * j]     = s0 | ((d0 & (BNODES - 1)) << 20);
        bk[2 * j]     = v0 ? (d0 >> BSH) : -1;
        eb[2 * j + 1] = s1 | ((d1 & (BNODES - 1)) << 20);
        bk[2 * j + 1] = v1 ? (d1 >> BSH) : -1;
        if (v0) atomicAdd(&cur[d0 >> BSH], 1);
        if (v1) atomicAdd(&cur[d1 >> BSH], 1);
    }
    __syncthreads();

    // exclusive scan of cur(=hist)[0..1024), 4 bins/thread
    const int t4 = tid * 4;
    int s0 = cur[t4], s1 = cur[t4 + 1], s2 = cur[t4 + 2], s3 = cur[t4 + 3];
    int my = s0 + s1 + s2 + s3;
    tsum[tid] = my;
    __syncthreads();
    for (int off = 1; off < 256; off <<= 1) {
        int t = (tid >= off) ? tsum[tid - off] : 0;
        __syncthreads();
        tsum[tid] += t;
        __syncthreads();
    }
    int ex = tsum[tid] - my;
    offs[t4] = ex;
    offs[t4 + 1] = ex + s0;
    offs[t4 + 2] = ex + s0 + s1;
    offs[t4 + 3] = ex + s0 + s1 + s2;
    __syncthreads();
    for (int b = tid; b < 1024; b += 256) cur[b] = offs[b];  // cursors
    __syncthreads();

    // scatter from registers into grouped sbuf
#pragma unroll
    for (int j = 0; j < 8; ++j) {
        if (bk[j] >= 0) {
            int slot = atomicAdd(&cur[bk[j]], 1);
            sbuf[slot] = eb[j];
        }
    }
    __syncthreads();

    // flush one run per thread (contiguous addresses -> L2 line merge)
    for (int b = tid; b < nbuckets; b += 256) {
        int beg = offs[b];
        int len = cur[b] - beg;
        if (len <= 0) continue;
        int g = atomicAdd(&gcnt[b], len);
        if (g >= CAP) continue;
        if (g + len > CAP) len = CAP - g;
        unsigned int* dst = arena + (size_t)b * CAP + g;
        for (int j = 0; j < len; ++j) dst[j] = (unsigned int)sbuf[beg + j];
    }
}

// In-bucket counting sort by dlocal -> node-contiguous runs. Emits
// pkd[node] = {beg|(cnt<<22), bits(dinv)} and fp16 prescaled y = x*dinv rows.
__global__ __launch_bounds__(256) void k_sort(
        const int* __restrict__ gcnt, unsigned int* __restrict__ arena,
        const float* __restrict__ x, uint2* __restrict__ pkd,
        __half2* __restrict__ y2, int n) {
    __shared__ unsigned int sbuf[CAP];   // 16 KB
    __shared__ unsigned int obuf[CAP];   // 16 KB
    __shared__ int hist[BNODES];
    __shared__ int offs[BNODES];
    __shared__ int cur[BNODES];
    __shared__ float rinv[BNODES];
    const int b = blockIdx.x, tid = threadIdx.x;
    const int count = min(gcnt[b], CAP);
    unsigned int* ent = arena + (size_t)b * CAP;

    if (tid < BNODES) hist[tid] = 0;
    __syncthreads();
    for (int p = tid; p < count; p += 256) {
        unsigned int v = ent[p];
        sbuf[p] = v;
        atomicAdd(&hist[v >> 20], 1);
    }
    __syncthreads();
    if (tid < BNODES) offs[tid] = hist[tid];
    __syncthreads();
    for (int off = 1; off < BNODES; off <<= 1) {
        int t = 0;
        if (tid < BNODES && tid >= off) t = offs[tid - off];
        __syncthreads();
        if (tid < BNODES) offs[tid] += t;
        __syncthreads();
    }
    if (tid < BNODES) {
        int ex = offs[tid] - hist[tid];   // exclusive
        cur[tid] = ex;
        float r = rsqrtf((float)(hist[tid] + 1));
        rinv[tid] = r;
        int node = b * BNODES + tid;
        if (node < n) {
            uint2 pd;
            pd.x = (unsigned int)(b * CAP + ex) | ((unsigned int)hist[tid] << 22);
            pd.y = __float_as_uint(r);
            pkd[node] = pd;
        }
    }
    __syncthreads();
    for (int p = tid; p < count; p += 256) {
        unsigned int v = sbuf[p];
        int pos = atomicAdd(&cur[v >> 20], 1);
        obuf[pos] = v;
    }
    // y write overlaps the sort scatter (independent of obuf)
    for (int idx = tid; idx < BNODES * 16; idx += 256) {
        int node = b * BNODES + (idx >> 4);
        if (node >= n) break;
        float r = rinv[idx >> 4];
        float2 v = ((const float2*)x)[(size_t)node * 16 + (idx & 15)];
        y2[(size_t)node * 16 + (idx & 15)] = __floats2half2_rn(v.x * r, v.y * r);
    }
    __syncthreads();
    for (int p = tid; p < count; p += 256) ent[p] = obuf[p];
}

// Fused (R15, proven): 8 lane-groups x 8 lanes (uint2 = 2 half2 / lane),
// PACKED fp16 accumulate, 3-step packed butterfly, dot2 m-phase. Prefetch:
// pd+self upfront; 4 masked ent words (deg<=32); next node's ent prefetched.
__global__ __launch_bounds__(256, 4) void k_fused(
        const unsigned int* __restrict__ arena, const uint2* __restrict__ pkd,
        const __half2* __restrict__ y2,
        const float* __restrict__ W1, const float* __restrict__ b1,
        const float* __restrict__ W2, const float* __restrict__ b2,
        float* __restrict__ out, int n) {
    __shared__ float sT[4][NMID];        // per-wave tanh row (1 KB)
    const int tid = threadIdx.x;
    const int wid = tid >> 6;
    const int lane = tid & 63;
    const int g = lane >> 3, l = lane & 7;   // 8 groups x 8 lanes
    const int jg = lane >> 3, k = lane & 7;  // epilogue mapping
    const char* y2c = (const char*)y2;

    // per-lane weight registers: W1 column as 16 packed half2
    unsigned w1h[16];
#pragma unroll
    for (int c2 = 0; c2 < 16; ++c2) {
        __half2 h = __floats2half2_rn(W1[(2 * c2) * NMID + lane],
                                      W1[(2 * c2 + 1) * NMID + lane]);
        w1h[c2] = __builtin_bit_cast(unsigned, h);
    }
    float w2row[8];
#pragma unroll
    for (int jj = 0; jj < 8; ++jj) w2row[jj] = W2[(jg * 8 + jj) * NACT + k];
    const float b1v = b1[lane];
    const float b2v = b2[k];

    const int nodeBase = blockIdx.x * (4 * NPW) + wid * NPW;

    // ---- prologue: prefetch pkd + self rows for all NPW nodes ----
    uint2 pd[NPW];
    uint2 sv[NPW];
#pragma unroll
    for (int nn = 0; nn < NPW; ++nn) {
        const int node = nodeBase + nn;
        const bool valid = node < n;
        pd[nn] = valid ? pkd[node] : make_uint2(0u, 0u);
        sv[nn] = make_uint2(0u, 0u);
        if (valid && g == 0) {
            unsigned off = ((unsigned)node << 6) | ((unsigned)l << 3);
            sv[nn] = *(const uint2*)(y2c + off);
        }
    }
    // prefetch 4 ent words for node 0 (covers entries 0..31)
    unsigned int en[4];
    {
        const unsigned beg0 = pd[0].x & 0x3FFFFF;
#pragma unroll
        for (int w = 0; w < 4; ++w) en[w] = arena[beg0 + g + 8 * w];
    }

#pragma unroll
    for (int nn = 0; nn < NPW; ++nn) {
        const int node = nodeBase + nn;       // wave-uniform
        const bool valid = node < n;          // wave-uniform

        const unsigned beg = pd[nn].x & 0x3FFFFF;
        const int cnt = valid ? (int)(pd[nn].x >> 22) : 0;
        const float din = __uint_as_float(pd[nn].y);

        // issue 4 masked row loads (entries g, g+8, g+16, g+24), 32b voffset
        bool ok[4];
        uint2 v[4];
#pragma unroll
        for (int w = 0; w < 4; ++w) {
            ok[w] = g + 8 * w < cnt;
            const unsigned idx = ok[w] ? (en[w] & 0xFFFFF) : 0u;
            const unsigned off = (idx << 6) | ((unsigned)l << 3);
            v[w] = *(const uint2*)(y2c + off);
        }

        // prefetch next node's ent words (overlaps this node's compute)
        if (nn + 1 < NPW) {
            const unsigned begN = pd[nn + 1].x & 0x3FFFFF;
#pragma unroll
            for (int w = 0; w < 4; ++w) en[w] = arena[begN + g + 8 * w];
        }

        // packed accumulate: acc0 = ch(4l,4l+1), acc1 = ch(4l+2,4l+3)
        unsigned acc0 = sv[nn].x, acc1 = sv[nn].y;  // self (g==0) or zero
#pragma unroll
        for (int w = 0; w < 4; ++w) {
            if (!ok[w]) { v[w].x = 0u; v[w].y = 0u; }
            acc0 = padd(acc0, v[w].x);
            acc1 = padd(acc1, v[w].y);
        }
        if (cnt > 32) {  // rare leftover (P ~ 1e-4 at mean deg 16)
            for (int i = 32 + g; i < cnt; i += 8) {
                unsigned ee = arena[beg + i];
                unsigned off = ((ee & 0xFFFFF) << 6) | ((unsigned)l << 3);
                uint2 vv = *(const uint2*)(y2c + off);
                acc0 = padd(acc0, vv.x);
                acc1 = padd(acc1, vv.y);
            }
        }
        // packed butterfly over lane bits 3..5 (6 shfl + 6 pk_add)
#pragma unroll
        for (int off = 8; off < 64; off <<= 1) {
            acc0 = padd(acc0, (unsigned)__shfl_xor((int)acc0, off));
            acc1 = padd(acc1, (unsigned)__shfl_xor((int)acc1, off));
        }

        // m-phase: lane s (s<8) holds ch 4s..4s+3 packed -> readlane + dot2.
        float sA = 0.f, sB = 0.f;
#pragma unroll
        for (int s = 0; s < 8; ++s) {
            sA = fdot2u(rlu(acc0, s), w1h[2 * s + 0], sA);
            sB = fdot2u(rlu(acc1, s), w1h[2 * s + 1], sB);
        }
        const float m = fmaf(din, sA + sB, b1v);  // din wave-uniform, folded
        sT[wid][lane] = fast_tanh(m);
        // wave-local handoff fence: DS write completed + no compiler reorder
        asm volatile("s_waitcnt lgkmcnt(0)" ::: "memory");
        __builtin_amdgcn_sched_barrier(0);

        // o-phase: 8 ds_read + 8 FMA + 3-step reduce
        float o = 0.f;
#pragma unroll
        for (int jj = 0; jj < 8; ++jj)
            o = fmaf(sT[wid][jg * 8 + jj], w2row[jj], o);
        o += __shfl_xor(o, 8);
        o += __shfl_xor(o, 16);
        o += __shfl_xor(o, 32);
        if (valid && jg == 0)
            out[(size_t)node * NACT + k] = o + b2v;
    }
}

extern "C" void kernel_launch(void* const* d_in, const int* in_sizes, int n_in,
                              void* d_out, int out_size, void* d_ws, size_t ws_size,
                              hipStream_t stream) {
    const float* x  = (const float*)d_in[0];
    const int*   ei = (const int*)d_in[1];
    const float* W1 = (const float*)d_in[2];
    const float* b1 = (const float*)d_in[3];
    const float* W2 = (const float*)d_in[4];
    const float* b2 = (const float*)d_in[5];
    float* out = (float*)d_out;

    const int n = in_sizes[0] / NOBS;       // 100000
    const long long e = in_sizes[1] / 2;    // 1600000
    const int B = (n + BNODES - 1) >> BSH;  // 782 buckets

    // ws layout (20.0 MB):
    //   gcnt int[1024] @0 | arena uint[B*CAP] @4096 | pkd uint2[n]
    //   | y2 half2[n*16]
    char* ws = (char*)d_ws;
    int*          gcnt  = (int*)ws;
    unsigned int* arena = (unsigned int*)(ws + 4096);
    uint2*        pkd   = (uint2*)(ws + 4096 + (size_t)B * ARENA_B);
    __half2*      y2    = (__half2*)(ws + 4096 + (size_t)B * ARENA_B + (size_t)n * 8);

    hipMemsetAsync(gcnt, 0, 4096, stream);
    int nsb = (int)((e + SPLIT_E - 1) / SPLIT_E);
    k_split<<<nsb, 256, 0, stream>>>(ei, gcnt, arena, e, B);
    k_sort<<<B, 256, 0, stream>>>(gcnt, arena, x, pkd, y2, n);
    const int npb = 4 * NPW;  // nodes per block
    k_fused<<<(n + npb - 1) / npb, 256, 0, stream>>>(arena, pkd, y2,
                                                     W1, b1, W2, b2, out, n);
}

// Round 19
// 78.728 us; speedup vs baseline: 1.2494x; 1.2494x over previous
//
#include <hip/hip_runtime.h>
#include <hip/hip_fp16.h>
#include <math.h>

// GCNConv QNet: out = tanh( (segsum(x[src]*norm, dst) + selfloop) @ W1 + b1 ) @ W2 + b2
// norm = dinv[src]*dinv[dst], dinv = rsqrt(in_degree + 1).
// Aggregation in 32-dim obs space (W1 applied AFTER segment_sum — linearity).
// R19: SPLIT_E back to 4096 (R18's 2048 shrank arena runs 5.2->2.6 and
// regressed k_split by 14us). Occupancy instead via 512 threads/block in
// k_split (8 edges/thread, 12 waves/CU) and k_sort. k_fused = R15 verbatim.

#define NOBS 32
#define NMID 64
#define NACT 8
#define BSH 7
#define BNODES 128           // nodes per bucket
#define CAP 4096             // max entries per bucket (mean ~2046)
#define ARENA_B 16384        // bytes per bucket arena (= CAP*4)
#define SPLIT_E 4096         // edges per split block
#define NPW 4                // nodes per wave in k_fused

typedef _Float16 half2v __attribute__((ext_vector_type(2)));

__device__ __forceinline__ bool edges_i64(const int* ei) {
    return (ei[1] | ei[3] | ei[5] | ei[7]) == 0;
}

// tanh(x) = 1 - 2/(1+e^{2x}); exact at +-inf, ~1e-5 rel err, branch-free.
__device__ __forceinline__ float fast_tanh(float x) {
    float t = __expf(2.f * x);
    return 1.f - 2.f * __builtin_amdgcn_rcpf(1.f + t);
}

__device__ __forceinline__ unsigned rlu(unsigned v, int lane) {
    return (unsigned)__builtin_amdgcn_readlane((int)v, lane);
}

// packed half2 add on raw bits (v_pk_add_f16)
__device__ __forceinline__ unsigned padd(unsigned a, unsigned b) {
    __half2 r = __hadd2(__builtin_bit_cast(__half2, a),
                        __builtin_bit_cast(__half2, b));
    return __builtin_bit_cast(unsigned, r);
}

// c += a.x*b.x + a.y*b.y in f32 (v_dot2_f32_f16)
__device__ __forceinline__ float fdot2u(unsigned a, unsigned b, float c) {
    return __builtin_amdgcn_fdot2(__builtin_bit_cast(half2v, a),
                                  __builtin_bit_cast(half2v, b), c, false);
}

// Multisplit: bin 4096 edges by dst-bucket, 512 threads (8 edges/thread).
__global__ __launch_bounds__(512) void k_split(
        const int* __restrict__ ei, int* __restrict__ gcnt,
        unsigned int* __restrict__ arena, long long e, int nbuckets) {
    __shared__ int sbuf[SPLIT_E];   // bucket-grouped entries (16 KB)
    __shared__ int offs[1024];
    __shared__ int cur[1024];
    __shared__ int tsum[512];
    const int tid = threadIdx.x;
    int eb[8];
    int bk[8];

    for (int b = tid; b < 1024; b += 512) cur[b] = 0;  // cur = hist
    __syncthreads();

    const long long base = (long long)blockIdx.x * SPLIT_E;
    const bool i64 = edges_i64(ei);
    const long long* e64 = (const long long*)ei;
#pragma unroll
    for (int j = 0; j < 4; ++j) {
        const int kk = j * 1024 + tid * 2;
        const long long ge = base + kk;
        const bool v0 = ge < e, v1 = ge + 1 < e;
        int s0 = 0, d0 = 0, s1 = 0, d1 = 0;
        if (v1) {  // paired loads
            if (i64) {
                ulonglong2 sp = *(const ulonglong2*)(e64 + ge);
                ulonglong2 dp = *(const ulonglong2*)(e64 + e + ge);
                s0 = (int)sp.x; s1 = (int)sp.y; d0 = (int)dp.x; d1 = (int)dp.y;
            } else {
                int2 sp = *(const int2*)(ei + ge);
                int2 dp = *(const int2*)(ei + e + ge);
                s0 = sp.x; s1 = sp.y; d0 = dp.x; d1 = dp.y;
            }
        } else if (v0) {
            if (i64) { s0 = (int)e64[ge]; d0 = (int)e64[e + ge]; }
            else     { s0 = ei[ge];       d0 = ei[e + ge]; }
        }
        eb[2 * j]     = s0 | ((d0 & (BNODES - 1)) << 20);
        bk[2 * j]     = v0 ? (d0 >> BSH) : -1;
        eb[2 * j + 1] = s1 | ((d1 & (BNODES - 1)) << 20);
        bk[2 * j + 1] = v1 ? (d1 >> BSH) : -1;
        if (v0) atomicAdd(&cur[d0 >> BSH], 1);
        if (v1) atomicAdd(&cur[d1 >> BSH], 1);
    }
    __syncthreads();

    // exclusive scan of cur(=hist)[0..1024), 2 bins/thread
    const int t2 = tid * 2;
    int s0 = cur[t2], s1 = cur[t2 + 1];
    int my = s0 + s1;
    tsum[tid] = my;
    __syncthreads();
    for (int off = 1; off < 512; off <<= 1) {
        int t = (tid >= off) ? tsum[tid - off] : 0;
        __syncthreads();
        tsum[tid] += t;
        __syncthreads();
    }
    int ex = tsum[tid] - my;
    offs[t2] = ex;
    offs[t2 + 1] = ex + s0;
    __syncthreads();
    for (int b = tid; b < 1024; b += 512) cur[b] = offs[b];  // cursors
    __syncthreads();

    // scatter from registers into grouped sbuf
#pragma unroll
    for (int j = 0; j < 8; ++j) {
        if (bk[j] >= 0) {
            int slot = atomicAdd(&cur[bk[j]], 1);
            sbuf[slot] = eb[j];
        }
    }
    __syncthreads();

    // flush one run per thread (contiguous addresses -> L2 line merge)
    for (int b = tid; b < nbuckets; b += 512) {
        int beg = offs[b];
        int len = cur[b] - beg;
        if (len <= 0) continue;
        int g = atomicAdd(&gcnt[b], len);
        if (g >= CAP) continue;
        if (g + len > CAP) len = CAP - g;
        unsigned int* dst = arena + (size_t)b * CAP + g;
        for (int j = 0; j < len; ++j) dst[j] = (unsigned int)sbuf[beg + j];
    }
}

// In-bucket counting sort by dlocal -> node-contiguous runs, 512 threads.
// Emits pkd[node] = {beg|(cnt<<22), bits(dinv)} and fp16 y = x*dinv rows.
__global__ __launch_bounds__(512) void k_sort(
        const int* __restrict__ gcnt, unsigned int* __restrict__ arena,
        const float* __restrict__ x, uint2* __restrict__ pkd,
        __half2* __restrict__ y2, int n) {
    __shared__ unsigned int sbuf[CAP];   // 16 KB
    __shared__ unsigned int obuf[CAP];   // 16 KB
    __shared__ int hist[BNODES];
    __shared__ int offs[BNODES];
    __shared__ int cur[BNODES];
    __shared__ float rinv[BNODES];
    const int b = blockIdx.x, tid = threadIdx.x;
    const int count = min(gcnt[b], CAP);
    unsigned int* ent = arena + (size_t)b * CAP;

    if (tid < BNODES) hist[tid] = 0;
    __syncthreads();
    for (int p = tid; p < count; p += 512) {
        unsigned int v = ent[p];
        sbuf[p] = v;
        atomicAdd(&hist[v >> 20], 1);
    }
    __syncthreads();
    if (tid < BNODES) offs[tid] = hist[tid];
    __syncthreads();
    for (int off = 1; off < BNODES; off <<= 1) {
        int t = 0;
        if (tid < BNODES && tid >= off) t = offs[tid - off];
        __syncthreads();
        if (tid < BNODES) offs[tid] += t;
        __syncthreads();
    }
    if (tid < BNODES) {
        int ex = offs[tid] - hist[tid];   // exclusive
        cur[tid] = ex;
        float r = rsqrtf((float)(hist[tid] + 1));
        rinv[tid] = r;
        int node = b * BNODES + tid;
        if (node < n) {
            uint2 pd;
            pd.x = (unsigned int)(b * CAP + ex) | ((unsigned int)hist[tid] << 22);
            pd.y = __float_as_uint(r);
            pkd[node] = pd;
        }
    }
    __syncthreads();
    for (int p = tid; p < count; p += 512) {
        unsigned int v = sbuf[p];
        int pos = atomicAdd(&cur[v >> 20], 1);
        obuf[pos] = v;
    }
    // y write overlaps the sort scatter (independent of obuf)
    for (int idx = tid; idx < BNODES * 16; idx += 512) {
        int node = b * BNODES + (idx >> 4);
        if (node >= n) break;
        float r = rinv[idx >> 4];
        float2 v = ((const float2*)x)[(size_t)node * 16 + (idx & 15)];
        y2[(size_t)node * 16 + (idx & 15)] = __floats2half2_rn(v.x * r, v.y * r);
    }
    __syncthreads();
    for (int p = tid; p < count; p += 512) ent[p] = obuf[p];
}

// Fused (R15, proven): 8 lane-groups x 8 lanes (uint2 = 2 half2 / lane),
// PACKED fp16 accumulate, 3-step packed butterfly, dot2 m-phase. Prefetch:
// pd+self upfront; 4 masked ent words (deg<=32); next node's ent prefetched.
__global__ __launch_bounds__(256, 4) void k_fused(
        const unsigned int* __restrict__ arena, const uint2* __restrict__ pkd,
        const __half2* __restrict__ y2,
        const float* __restrict__ W1, const float* __restrict__ b1,
        const float* __restrict__ W2, const float* __restrict__ b2,
        float* __restrict__ out, int n) {
    __shared__ float sT[4][NMID];        // per-wave tanh row (1 KB)
    const int tid = threadIdx.x;
    const int wid = tid >> 6;
    const int lane = tid & 63;
    const int g = lane >> 3, l = lane & 7;   // 8 groups x 8 lanes
    const int jg = lane >> 3, k = lane & 7;  // epilogue mapping
    const char* y2c = (const char*)y2;

    // per-lane weight registers: W1 column as 16 packed half2
    unsigned w1h[16];
#pragma unroll
    for (int c2 = 0; c2 < 16; ++c2) {
        __half2 h = __floats2half2_rn(W1[(2 * c2) * NMID + lane],
                                      W1[(2 * c2 + 1) * NMID + lane]);
        w1h[c2] = __builtin_bit_cast(unsigned, h);
    }
    float w2row[8];
#pragma unroll
    for (int jj = 0; jj < 8; ++jj) w2row[jj] = W2[(jg * 8 + jj) * NACT + k];
    const float b1v = b1[lane];
    const float b2v = b2[k];

    const int nodeBase = blockIdx.x * (4 * NPW) + wid * NPW;

    // ---- prologue: prefetch pkd + self rows for all NPW nodes ----
    uint2 pd[NPW];
    uint2 sv[NPW];
#pragma unroll
    for (int nn = 0; nn < NPW; ++nn) {
        const int node = nodeBase + nn;
        const bool valid = node < n;
        pd[nn] = valid ? pkd[node] : make_uint2(0u, 0u);
        sv[nn] = make_uint2(0u, 0u);
        if (valid && g == 0) {
            unsigned off = ((unsigned)node << 6) | ((unsigned)l << 3);
            sv[nn] = *(const uint2*)(y2c + off);
        }
    }
    // prefetch 4 ent words for node 0 (covers entries 0..31)
    unsigned int en[4];
    {
        const unsigned beg0 = pd[0].x & 0x3FFFFF;
#pragma unroll
        for (int w = 0; w < 4; ++w) en[w] = arena[beg0 + g + 8 * w];
    }

#pragma unroll
    for (int nn = 0; nn < NPW; ++nn) {
        const int node = nodeBase + nn;       // wave-uniform
        const bool valid = node < n;          // wave-uniform

        const unsigned beg = pd[nn].x & 0x3FFFFF;
        const int cnt = valid ? (int)(pd[nn].x >> 22) : 0;
        const float din = __uint_as_float(pd[nn].y);

        // issue 4 masked row loads (entries g, g+8, g+16, g+24), 32b voffset
        bool ok[4];
        uint2 v[4];
#pragma unroll
        for (int w = 0; w < 4; ++w) {
            ok[w] = g + 8 * w < cnt;
            const unsigned idx = ok[w] ? (en[w] & 0xFFFFF) : 0u;
            const unsigned off = (idx << 6) | ((unsigned)l << 3);
            v[w] = *(const uint2*)(y2c + off);
        }

        // prefetch next node's ent words (overlaps this node's compute)
        if (nn + 1 < NPW) {
            const unsigned begN = pd[nn + 1].x & 0x3FFFFF;
#pragma unroll
            for (int w = 0; w < 4; ++w) en[w] = arena[begN + g + 8 * w];
        }

        // packed accumulate: acc0 = ch(4l,4l+1), acc1 = ch(4l+2,4l+3)
        unsigned acc0 = sv[nn].x, acc1 = sv[nn].y;  // self (g==0) or zero
#pragma unroll
        for (int w = 0; w < 4; ++w) {
            if (!ok[w]) { v[w].x = 0u; v[w].y = 0u; }
            acc0 = padd(acc0, v[w].x);
            acc1 = padd(acc1, v[w].y);
        }
        if (cnt > 32) {  // rare leftover (P ~ 1e-4 at mean deg 16)
            for (int i = 32 + g; i < cnt; i += 8) {
                unsigned ee = arena[beg + i];
                unsigned off = ((ee & 0xFFFFF) << 6) | ((unsigned)l << 3);
                uint2 vv = *(const uint2*)(y2c + off);
                acc0 = padd(acc0, vv.x);
                acc1 = padd(acc1, vv.y);
            }
        }
        // packed butterfly over lane bits 3..5 (6 shfl + 6 pk_add)
#pragma unroll
        for (int off = 8; off < 64; off <<= 1) {
            acc0 = padd(acc0, (unsigned)__shfl_xor((int)acc0, off));
            acc1 = padd(acc1, (unsigned)__shfl_xor((int)acc1, off));
        }

        // m-phase: lane s (s<8) holds ch 4s..4s+3 packed -> readlane + dot2.
        float sA = 0.f, sB = 0.f;
#pragma unroll
        for (int s = 0; s < 8; ++s) {
            sA = fdot2u(rlu(acc0, s), w1h[2 * s + 0], sA);
            sB = fdot2u(rlu(acc1, s), w1h[2 * s + 1], sB);
        }
        const float m = fmaf(din, sA + sB, b1v);  // din wave-uniform, folded
        sT[wid][lane] = fast_tanh(m);
        // wave-local handoff fence: DS write completed + no compiler reorder
        asm volatile("s_waitcnt lgkmcnt(0)" ::: "memory");
        __builtin_amdgcn_sched_barrier(0);

        // o-phase: 8 ds_read + 8 FMA + 3-step reduce
        float o = 0.f;
#pragma unroll
        for (int jj = 0; jj < 8; ++jj)
            o = fmaf(sT[wid][jg * 8 + jj], w2row[jj], o);
        o += __shfl_xor(o, 8);
        o += __shfl_xor(o, 16);
        o += __shfl_xor(o, 32);
        if (valid && jg == 0)
            out[(size_t)node * NACT + k] = o + b2v;
    }
}

extern "C" void kernel_launch(void* const* d_in, const int* in_sizes, int n_in,
                              void* d_out, int out_size, void* d_ws, size_t ws_size,
                              hipStream_t stream) {
    const float* x  = (const float*)d_in[0];
    const int*   ei = (const int*)d_in[1];
    const float* W1 = (const float*)d_in[2];
    const float* b1 = (const float*)d_in[3];
    const float* W2 = (const float*)d_in[4];
    const float* b2 = (const float*)d_in[5];
    float* out = (float*)d_out;

    const int n = in_sizes[0] / NOBS;       // 100000
    const long long e = in_sizes[1] / 2;    // 1600000
    const int B = (n + BNODES - 1) >> BSH;  // 782 buckets

    // ws layout (20.0 MB):
    //   gcnt int[1024] @0 | arena uint[B*CAP] @4096 | pkd uint2[n]
    //   | y2 half2[n*16]
    char* ws = (char*)d_ws;
    int*          gcnt  = (int*)ws;
    unsigned int* arena = (unsigned int*)(ws + 4096);
    uint2*        pkd   = (uint2*)(ws + 4096 + (size_t)B * ARENA_B);
    __half2*      y2    = (__half2*)(ws + 4096 + (size_t)B * ARENA_B + (size_t)n * 8);

    hipMemsetAsync(gcnt, 0, 4096, stream);
    int nsb = (int)((e + SPLIT_E - 1) / SPLIT_E);
    k_split<<<nsb, 512, 0, stream>>>(ei, gcnt, arena, e, B);
    k_sort<<<B, 512, 0, stream>>>(gcnt, arena, x, pkd, y2, n);
    const int npb = 4 * NPW;  // nodes per block
    k_fused<<<(n + npb - 1) / npb, 256, 0, stream>>>(arena, pkd, y2,
                                                     W1, b1, W2, b2, out, n);
}